// Round 7
// baseline (82168.671 us; speedup 1.0000x reference)
//
#include <hip/hip_runtime.h>
#include <cmath>

#define NN 68

// DPP move with compile-time control (quad_perm / row_ror)
template <int CTRL>
__device__ __forceinline__ float dppf(float x) {
    return __int_as_float(
        __builtin_amdgcn_mov_dpp(__float_as_int(x), CTRL, 0xF, 0xF, true));
}

#if __has_builtin(__builtin_amdgcn_exp2f)
#define FAST_EXP2(x) __builtin_amdgcn_exp2f(x)
#else
#define FAST_EXP2(x) exp2f(x)
#endif
#define FAST_RCP(x) __builtin_amdgcn_rcpf(x)

#define MAC4(c, e)                    \
    a0 = fmaf(c.x, e.x, a0);          \
    a1 = fmaf(c.y, e.y, a1);          \
    a2 = fmaf(c.z, e.z, a2);          \
    a3 = fmaf(c.w, e.w, a3);

// Full-wave sum of r_{l&3}: quad transpose-reduce (xor1, xor2 + selects),
// then row rotations (4,8) and cross-row xors (16,32). Result: every lane
// holds sum over all 64 lanes of r_{lane&3}.
#define REDUCE4(v, r0, r1, r2, r3)                                  \
    {                                                               \
        float q0 = r0 + dppf<0xB1>(r0);                             \
        float q1 = r1 + dppf<0xB1>(r1);                             \
        float q2 = r2 + dppf<0xB1>(r2);                             \
        float q3 = r3 + dppf<0xB1>(r3);                             \
        q0 += dppf<0x4E>(q0);                                       \
        q1 += dppf<0x4E>(q1);                                       \
        q2 += dppf<0x4E>(q2);                                       \
        q3 += dppf<0x4E>(q3);                                       \
        const float va = odd1 ? q1 : q0;                            \
        const float vb = odd1 ? q3 : q2;                            \
        float vv = odd2 ? vb : va;                                  \
        vv += dppf<0x124>(vv);   /* row_ror:4  */                   \
        vv += dppf<0x128>(vv);   /* row_ror:8  */                   \
        vv += __shfl_xor(vv, 16);                                   \
        vv += __shfl_xor(vv, 32);                                   \
        v = vv;                                                     \
    }

__global__ __launch_bounds__(64, 1)
void nmm_kernel(const float* __restrict__ params,
                const float* __restrict__ Cjk,
                const float* __restrict__ y0,
                float* __restrict__ out,
                const int num_steps)
{
#pragma clang fp contract(off)
    const int l = threadIdx.x;            // lane 0..63, node l
    const bool odd1 = (l & 1) != 0;       // loop-invariant select masks
    const bool odd2 = (l & 2) != 0;

    // [2] double buffer; [0..67] real E, [68..127] dump region for the
    // unconditional secondary writes of lanes 4..63
    __shared__ __align__(16) float Ebuf[2][128];

    const float tau_e = params[0], tau_i = params[1];
    const float P1 = params[2], P2 = params[3], P3 = params[4];
    const float P4 = params[5], P5 = params[6], Pp = params[7];
    const float kE = params[8], kI = params[9];

    const float LOG2E = 1.4426950408889634f;
    const float kE2 = -1.3f * LOG2E, bE2 = (1.3f * 4.0f) * LOG2E;
    const float kI2 = -2.0f * LOG2E, bI2 = (2.0f * 3.7f) * LOG2E;
    const float s0E = 1.0f / (1.0f + expf(5.2f));
    const float s0I = 1.0f / (1.0f + expf(7.4f));
    const float inv_te = 1.0f / tau_e, inv_ti = 1.0f / tau_i;

    // Primary C row l in registers: 17 float4 (row stride 272 B = 16B-aligned)
    const float4* cr4 = (const float4*)(Cjk + l * NN);
    float4 c0 = cr4[0],  c1 = cr4[1],  c2 = cr4[2],  c3 = cr4[3];
    float4 c4 = cr4[4],  c5 = cr4[5],  c6 = cr4[6],  c7 = cr4[7];
    float4 c8 = cr4[8],  c9 = cr4[9],  c10 = cr4[10], c11 = cr4[11];
    float4 c12 = cr4[12], c13 = cr4[13], c14 = cr4[14], c15 = cr4[15];
    float4 c16 = cr4[16];

    // Secondary rows 64..67: lane l holds column l of each (cs_g), and
    // lanes 0..3 hold the 4x4 corner block (ccr_g = C[64+g][64+l])
    const float cs0 = Cjk[64 * NN + l];
    const float cs1 = Cjk[65 * NN + l];
    const float cs2 = Cjk[66 * NN + l];
    const float cs3 = Cjk[67 * NN + l];
    float ccr0 = 0.f, ccr1 = 0.f, ccr2 = 0.f, ccr3 = 0.f;
    if (l < 4) {
        ccr0 = Cjk[64 * NN + 64 + l];
        ccr1 = Cjk[65 * NN + 64 + l];
        ccr2 = Cjk[66 * NN + 64 + l];
        ccr3 = Cjk[67 * NN + 64 + l];
    }

    // State: node l (primary) and node 64+(l&3) (secondary, redundant across
    // lane groups -- every lane evolves TRUE dynamics, so no garbage values)
    float E  = y0[l];
    float I  = y0[NN + l];
    float E2 = y0[64 + (l & 3)];
    float I2 = y0[NN + 64 + (l & 3)];

    // Ebuf[0] = E_0 (reference step 0 uses E_prev = y0[:N])
    Ebuf[0][l] = E;
    Ebuf[0][64 + l] = E2;   // lanes 0..3 -> slots 64..67; others -> dump

    // Prologue: conn2 for step 0 = rows 64..67 of C @ E_0
    float conn2;
    {
        float r0 = cs0 * E; r0 = fmaf(ccr0, E2, r0);
        float r1 = cs1 * E; r1 = fmaf(ccr1, E2, r1);
        float r2 = cs2 * E; r2 = fmaf(ccr2, E2, r2);
        float r3 = cs3 * E; r3 = fmaf(ccr3, E2, r3);
        REDUCE4(conn2, r0, r1, r2, r3)
    }

    float* outP = out + (size_t)l * (size_t)num_steps;
    float* outS = out + (size_t)(64 + (l & 3)) * (size_t)num_steps;

    // One Euler step. No s_barrier anywhere: single wave, LDS pipe is
    // in-order per wave, so write->read ordering is program order.
#define STEP(P, DA, DB)                                                       \
    {                                                                         \
        /* 1) broadcast-read E_{t-1} quads (same addr all lanes: no bank */   \
        /*    conflicts); latency hidden under secondary partials below  */   \
        const float4* eb = (const float4*)Ebuf[P];                            \
        const float4 e0 = eb[0],  e1 = eb[1],  e2 = eb[2],  e3 = eb[3];       \
        const float4 e4 = eb[4],  e5 = eb[5],  e6 = eb[6],  e7 = eb[7];       \
        const float4 e8 = eb[8],  e9 = eb[9],  e10 = eb[10], e11 = eb[11];    \
        const float4 e12 = eb[12], e13 = eb[13], e14 = eb[14], e15 = eb[15];  \
        const float4 e16 = eb[16];                                            \
        /* 2) publish E_t for next step (other buffer; in-order pipe) */      \
        Ebuf[(P) ^ 1][l] = E;                                                 \
        Ebuf[(P) ^ 1][64 + l] = E2;                                           \
        /* 3) secondary partials from E_t -> conn2 for NEXT step */           \
        float r0 = cs0 * E; r0 = fmaf(ccr0, E2, r0);                          \
        float r1 = cs1 * E; r1 = fmaf(ccr1, E2, r1);                          \
        float r2 = cs2 * E; r2 = fmaf(ccr2, E2, r2);                          \
        float r3 = cs3 * E; r3 = fmaf(ccr3, E2, r3);                          \
        /* 4) primary conn_t = C-row(l) . E_{t-1} */                          \
        float a0 = 0.f, a1 = 0.f, a2 = 0.f, a3 = 0.f;                         \
        MAC4(c0, e0)  MAC4(c1, e1)  MAC4(c2, e2)  MAC4(c3, e3)                \
        MAC4(c4, e4)  MAC4(c5, e5)  MAC4(c6, e6)  MAC4(c7, e7)                \
        MAC4(c8, e8)  MAC4(c9, e9)  MAC4(c10, e10) MAC4(c11, e11)             \
        MAC4(c12, e12) MAC4(c13, e13) MAC4(c14, e14) MAC4(c15, e15)           \
        MAC4(c16, e16)                                                        \
        const float conn = (a0 + a1) + (a2 + a3);                             \
        /* 5) primary elementwise (round-4 validated math) */                 \
        const float xE = P1 * E - P2 * I + P5 * conn + Pp;                    \
        const float Se = FAST_RCP(1.0f + FAST_EXP2(fmaf(kE2, xE, bE2))) - s0E;\
        const float xI = P3 * E - P4 * I;                                     \
        const float Si = FAST_RCP(1.0f + FAST_EXP2(fmaf(kI2, xI, bI2))) - s0I;\
        const float En = fmaf(fmaf(kE - E, Se, -E), inv_te, E);               \
        const float In = fmaf(fmaf(kI - I, Si, -I), inv_ti, I);               \
        /* 6) secondary elementwise with carried conn2 */                     \
        const float xE2 = P1 * E2 - P2 * I2 + P5 * conn2 + Pp;                \
        const float Se2 = FAST_RCP(1.0f + FAST_EXP2(fmaf(kE2, xE2, bE2))) - s0E;\
        const float xI2 = P3 * E2 - P4 * I2;                                  \
        const float Si2 = FAST_RCP(1.0f + FAST_EXP2(fmaf(kI2, xI2, bI2))) - s0I;\
        const float En2 = fmaf(fmaf(kE - E2, Se2, -E2), inv_te, E2);          \
        const float In2 = fmaf(fmaf(kI - I2, Si2, -I2), inv_ti, I2);          \
        DA = En - In; DB = En2 - In2;                                         \
        /* 7) reduce partials -> conn2 (consumed next step: full-step slack)*/\
        REDUCE4(conn2, r0, r1, r2, r3)                                        \
        E = En; I = In; E2 = En2; I2 = In2;                                   \
    }

    int t = 0;
    for (; t + 3 < num_steps; t += 4) {
        float dA0, dA1, dA2, dA3, dB0, dB1, dB2, dB3;
        STEP(0, dA0, dB0)
        STEP(1, dA1, dB1)
        STEP(0, dA2, dB2)
        STEP(1, dA3, dB3)
        *(float4*)(outP + t) = make_float4(dA0, dA1, dA2, dA3);
        if (l < 4) *(float4*)(outS + t) = make_float4(dB0, dB1, dB2, dB3);
    }
    for (; t < num_steps; ++t) {
        float dA, dB;
        STEP((t & 1), dA, dB)
        outP[t] = dA;
        if (l < 4) outS[t] = dB;
    }
#undef STEP
}

extern "C" void kernel_launch(void* const* d_in, const int* in_sizes, int n_in,
                              void* d_out, int out_size, void* d_ws, size_t ws_size,
                              hipStream_t stream) {
    const float* params = (const float*)d_in[0];
    const float* Cjk    = (const float*)d_in[1];
    const float* y0     = (const float*)d_in[2];
    const int num_steps = out_size / NN;

    nmm_kernel<<<dim3(1), dim3(64), 0, stream>>>(
        params, Cjk, y0, (float*)d_out, num_steps);
}

// Round 8
// 44291.418 us; speedup vs baseline: 1.8552x; 1.8552x over previous
//
#include <hip/hip_runtime.h>
#include <cmath>

#define NN   68     // nodes
#define NPAD 72     // E buffer padded to 2 chunks of 36 (144 B, 16B-aligned)
#define HALF 36     // K-chunk per thread
#define NT   136    // 2 threads per node (K-split), 3 waves

// lane XOR 1 within quad via DPP quad_perm [1,0,3,2] -- pure VALU, no LDS
__device__ __forceinline__ float dpp_xor1(float x) {
    return __int_as_float(
        __builtin_amdgcn_mov_dpp(__float_as_int(x), 0xB1, 0xF, 0xF, true));
}

#if __has_builtin(__builtin_amdgcn_exp2f)
#define FAST_EXP2(x) __builtin_amdgcn_exp2f(x)
#else
#define FAST_EXP2(x) exp2f(x)
#endif
#define FAST_RCP(x) __builtin_amdgcn_rcpf(x)

#define MAC(q, e)                 \
    a0 = fmaf(q.x, e.x, a0);      \
    a1 = fmaf(q.y, e.y, a1);      \
    a2 = fmaf(q.z, e.z, a2);      \
    a3 = fmaf(q.w, e.w, a3);

// full dot product of this lane's C half-row with the 36-float chunk of BUF;
// after dpp_xor1 both K-split lanes of the pair hold the complete sum
#define MATVEC(BUF, CONN)                                                     \
    {                                                                         \
        const float* eb = &(BUF)[s * HALF];                                   \
        const float4 e0 = ((const float4*)eb)[0], e1 = ((const float4*)eb)[1],\
                     e2 = ((const float4*)eb)[2], e3 = ((const float4*)eb)[3],\
                     e4 = ((const float4*)eb)[4], e5 = ((const float4*)eb)[5],\
                     e6 = ((const float4*)eb)[6], e7 = ((const float4*)eb)[7],\
                     e8 = ((const float4*)eb)[8];                             \
        float a0 = 0.f, a1 = 0.f, a2 = 0.f, a3 = 0.f;                         \
        MAC(q0, e0) MAC(q1, e1) MAC(q2, e2) MAC(q3, e3) MAC(q4, e4)           \
        MAC(q5, e5) MAC(q6, e6) MAC(q7, e7) MAC(q8, e8)                       \
        const float pSum = (a0 + a1) + (a2 + a3);                             \
        CONN = pSum + dpp_xor1(pSum);                                         \
    }

// one Euler sub-step (round-4 validated fast math, absmax 0.0)
#define ELEM(Ein, Iin, CONN, Eout, Iout)                                      \
    {                                                                         \
        const float xE = P1 * (Ein) - P2 * (Iin) + P5 * (CONN) + Pp;          \
        const float Se = FAST_RCP(1.0f + FAST_EXP2(fmaf(kE2, xE, bE2))) - s0E;\
        const float xI = P3 * (Ein) - P4 * (Iin);                             \
        const float Si = FAST_RCP(1.0f + FAST_EXP2(fmaf(kI2, xI, bI2))) - s0I;\
        Eout = fmaf(fmaf(kE - (Ein), Se, -(Ein)), inv_te, (Ein));             \
        Iout = fmaf(fmaf(kI - (Iin), Si, -(Iin)), inv_ti, (Iin));             \
    }

// SUPERSTEP: steps T and T+1 with ONE barrier.
// Reads pair (RA=E_{T-1}, RB=E_T); writes pair (WA=E_{T+1}, WB=E_{T+2}).
// Read/write pairs are distinct buffers -> no intra-superstep cross-wave race;
// the end barrier orders this superstep's writes before the next one's reads.
#define SUPER(RA, RB, WA, WB, T)                                              \
    {                                                                         \
        float conn1, conn2;                                                   \
        MATVEC(RA, conn1)              /* conn_T     = C @ E_{T-1} */         \
        MATVEC(RB, conn2)              /* conn_{T+1} = C @ E_T, independent */\
        float En1, In1, En2, In2;                                             \
        ELEM(E, I, conn1, En1, In1)    /* E_{T+1} */                          \
        ELEM(En1, In1, conn2, En2, In2) /* E_{T+2} */                         \
        WA[j] = En1; WB[j] = En2;      /* dup same-value write: free */       \
        if (s == 0) *(float2*)(op + (T)) = make_float2(En1 - In1, En2 - In2); \
        E = En2; I = In2;                                                     \
        asm volatile("s_waitcnt lgkmcnt(0)\ns_barrier" ::: "memory");         \
    }

__global__ __launch_bounds__(NT, 1)
void nmm_kernel(const float* __restrict__ params,
                const float* __restrict__ Cjk,
                const float* __restrict__ y0,
                float* __restrict__ out,
                const int num_steps)
{
#pragma clang fp contract(off)
    const int tid = threadIdx.x;
    const int j   = tid >> 1;    // node 0..67
    const int s   = tid & 1;     // K-half 0/1

    // 4 buffers: two (A,B) pairs ping-ponged per superstep
    __shared__ __align__(16) float A0[NPAD], B0[NPAD], A1[NPAD], B1[NPAD];

    const float tau_e = params[0], tau_i = params[1];
    const float P1 = params[2], P2 = params[3], P3 = params[4];
    const float P4 = params[5], P5 = params[6], Pp = params[7];
    const float kE = params[8], kI = params[9];

    const float LOG2E = 1.4426950408889634f;
    const float kE2 = -1.3f * LOG2E, bE2 = (1.3f * 4.0f) * LOG2E;
    const float kI2 = -2.0f * LOG2E, bI2 = (2.0f * 3.7f) * LOG2E;
    const float s0E = 1.0f / (1.0f + expf(5.2f));
    const float s0I = 1.0f / (1.0f + expf(7.4f));
    const float inv_te = 1.0f / tau_e, inv_ti = 1.0f / tau_i;

    // C-row half chunk -> 9 float4s (s=1 top quad is zero pad)
    const float* crow = Cjk + j * NN + s * HALF;
    const float4 q0 = *(const float4*)(crow +  0);
    const float4 q1 = *(const float4*)(crow +  4);
    const float4 q2 = *(const float4*)(crow +  8);
    const float4 q3 = *(const float4*)(crow + 12);
    const float4 q4 = *(const float4*)(crow + 16);
    const float4 q5 = *(const float4*)(crow + 20);
    const float4 q6 = *(const float4*)(crow + 24);
    const float4 q7 = *(const float4*)(crow + 28);
    const float4 q8 = (s == 0) ? *(const float4*)(crow + 32)
                               : make_float4(0.f, 0.f, 0.f, 0.f);

    // init: reference's step 0 AND step 1 both use C@E_0 (E_prev lags), so
    // pair0 = (E_0, E_0); pair1 only needs its persistent zero pads
    if (tid < NPAD) {
        const float e0v = (tid < NN) ? y0[tid] : 0.0f;
        A0[tid] = e0v; B0[tid] = e0v;
        A1[tid] = 0.0f; B1[tid] = 0.0f;
    }
    float E = y0[j];
    float I = y0[NN + j];
    asm volatile("s_waitcnt lgkmcnt(0)\ns_barrier" ::: "memory");

    float* op = out + (size_t)j * (size_t)num_steps;

    int t = 0;
    for (; t + 3 < num_steps; t += 4) {      // 2 supersteps, pairs alternate
        SUPER(A0, B0, A1, B1, t)
        SUPER(A1, B1, A0, B0, t + 2)
    }
    bool rp1 = false;                         // read-pair at loop exit: pair0
    if (t + 1 < num_steps) {                  // one more full superstep
        SUPER(A0, B0, A1, B1, t)
        t += 2; rp1 = true;
    }
    if (t < num_steps) {                      // final single step (odd tail)
        const float* RA = rp1 ? A1 : A0;      // holds E_{t-1}
        float conn1;
        MATVEC(RA, conn1)
        float En1, In1;
        ELEM(E, I, conn1, En1, In1)
        if (s == 0) op[t] = En1 - In1;
    }
}

extern "C" void kernel_launch(void* const* d_in, const int* in_sizes, int n_in,
                              void* d_out, int out_size, void* d_ws, size_t ws_size,
                              hipStream_t stream) {
    const float* params = (const float*)d_in[0];
    const float* Cjk    = (const float*)d_in[1];
    const float* y0     = (const float*)d_in[2];
    const int num_steps = out_size / NN;

    nmm_kernel<<<dim3(1), dim3(NT), 0, stream>>>(
        params, Cjk, y0, (float*)d_out, num_steps);
}